// Round 12
// baseline (187.133 us; speedup 1.0000x reference)
//
#include <hip/hip_runtime.h>
#include <hip/hip_fp16.h>

static inline int cdiv(int a, int b) { return (a + b - 1) / b; }

#define NWORD 25600   // 102400 B LDS = byte counters for N <= 102400
#define HC    64      // edge chunks (= hist blocks)
#define NBLK  256     // partition blocks
#define BKT_SHIFT 12  // 4096 csr slots per bucket

struct h2x4 { __half2 a, b, c, d; };  // 16 B = 8 halves

// ---------------- phase A: single-pass full-range LDS histogram + rank ----------------
__global__ __launch_bounds__(1024) void k_hist(const int* __restrict__ dst, int E, int N, int chunk,
                                               unsigned char* __restrict__ rank8,
                                               unsigned char* __restrict__ Mb) {
    __shared__ unsigned int cnt[NWORD];
    int c = blockIdx.x;
    for (int i = threadIdx.x; i < NWORD; i += 1024) cnt[i] = 0;
    __syncthreads();
    int ebeg = c * chunk;
    int eend = min(E, ebeg + chunk);
    for (int e = ebeg + threadIdx.x; e < eend; e += 1024) {
        int d = dst[e];
        int sh = (d & 3) * 8;
        unsigned int old = atomicAdd(&cnt[d >> 2], 1u << sh);  // LDS atomic
        rank8[e] = (unsigned char)((old >> sh) & 0xFF);
    }
    __syncthreads();
    unsigned int* Mrow = (unsigned int*)(Mb + (size_t)c * N);
    int nw = N >> 2;
    for (int i = threadIdx.x; i < nw; i += 1024) Mrow[i] = cnt[i];
}

// ---------------- deg + dinv + per-(chunk,node) byte prefix (fused) ----------------
__global__ __launch_bounds__(256) void k_degpre(const unsigned char* __restrict__ Mb, int N,
                                                unsigned char* __restrict__ pre8,
                                                int* __restrict__ deg, float* __restrict__ dinv) {
    int i = blockIdx.x * 256 + threadIdx.x;  // group of 4 nodes
    if (i >= (N >> 2)) return;
    unsigned int s0 = 0, s1 = 0, s2 = 0, s3 = 0;
#pragma unroll
    for (int c = 0; c < HC; ++c) {
        unsigned int w = *(const unsigned int*)(Mb + (size_t)c * N + 4 * i);
        *(unsigned int*)(pre8 + (size_t)c * N + 4 * i) = s0 | (s1 << 8) | (s2 << 16) | (s3 << 24);
        s0 += w & 0xFF; s1 += (w >> 8) & 0xFF; s2 += (w >> 16) & 0xFF; s3 += (w >> 24) & 0xFF;
    }
    ((int4*)deg)[i] = make_int4((int)s0, (int)s1, (int)s2, (int)s3);
    ((float4*)dinv)[i] = make_float4(rsqrtf((float)(s0 + 1)), rsqrtf((float)(s1 + 1)),
                                     rsqrtf((float)(s2 + 1)), rsqrtf((float)(s3 + 1)));
}

// ---------------- exclusive scan (hierarchical, generic length) ----------------
#define SCAN_BS 1024

__global__ __launch_bounds__(SCAN_BS) void k_blocksum(const int* __restrict__ deg, int N, int* __restrict__ bsum) {
    __shared__ int s[SCAN_BS];
    int t = threadIdx.x;
    int i = blockIdx.x * SCAN_BS + t;
    s[t] = (i < N) ? deg[i] : 0;
    __syncthreads();
    for (int off = SCAN_BS / 2; off > 0; off >>= 1) {
        if (t < off) s[t] += s[t + off];
        __syncthreads();
    }
    if (t == 0) bsum[blockIdx.x] = s[0];
}

__global__ __launch_bounds__(128) void k_scan_bsums(const int* __restrict__ bsum, int NB, int* __restrict__ boff) {
    __shared__ int s[128];
    int t = threadIdx.x;
    int v = (t < NB) ? bsum[t] : 0;
    s[t] = v;
    __syncthreads();
    for (int off = 1; off < 128; off <<= 1) {
        int u = (t >= off) ? s[t - off] : 0;
        __syncthreads();
        s[t] += u;
        __syncthreads();
    }
    if (t < NB) boff[t] = s[t] - v;  // exclusive
}

__global__ __launch_bounds__(SCAN_BS) void k_scan_final(const int* __restrict__ deg, int N,
                                                        const int* __restrict__ boff,
                                                        int* __restrict__ offsets, int E) {
    __shared__ int s[SCAN_BS];
    int t = threadIdx.x;
    int i = blockIdx.x * SCAN_BS + t;
    int v = (i < N) ? deg[i] : 0;
    s[t] = v;
    __syncthreads();
    for (int off = 1; off < SCAN_BS; off <<= 1) {
        int u = (t >= off) ? s[t - off] : 0;
        __syncthreads();
        s[t] += u;
        __syncthreads();
    }
    if (i < N) offsets[i] = boff[blockIdx.x] + s[t] - v;
    if (blockIdx.x == 0 && t == 0) offsets[N] = E;
}

// ---------------- k_pos: compute final CSR slot per edge (sequential write) + bucket hist ----------------
__global__ __launch_bounds__(256) void k_pos(const int* __restrict__ ei, int E, int N, int chunk, int epb, int nbuk,
                                             const int* __restrict__ offsets,
                                             const unsigned char* __restrict__ pre8,
                                             const unsigned char* __restrict__ rank8,
                                             int* __restrict__ posarr, int* __restrict__ cnt) {
    __shared__ int h[512];
    int blk = blockIdx.x;
    for (int b = threadIdx.x; b < nbuk; b += 256) h[b] = 0;
    __syncthreads();
    int beg = blk * epb;
    int end = min(E, beg + epb);
    const int* dst = ei + E;
    int e = beg + threadIdx.x;
    for (; e + 768 < end; e += 1024) {
        int e0 = e, e1 = e + 256, e2 = e + 512, e3 = e + 768;
        int d0 = dst[e0], d1 = dst[e1], d2 = dst[e2], d3 = dst[e3];
        int c0 = e0 / chunk, c1 = e1 / chunk, c2 = e2 / chunk, c3 = e3 / chunk;
        int o0 = offsets[d0], o1 = offsets[d1], o2 = offsets[d2], o3 = offsets[d3];
        int q0 = (int)pre8[(size_t)c0 * N + d0] + (int)rank8[e0];
        int q1 = (int)pre8[(size_t)c1 * N + d1] + (int)rank8[e1];
        int q2 = (int)pre8[(size_t)c2 * N + d2] + (int)rank8[e2];
        int q3 = (int)pre8[(size_t)c3 * N + d3] + (int)rank8[e3];
        int p0 = o0 + q0, p1 = o1 + q1, p2 = o2 + q2, p3 = o3 + q3;
        posarr[e0] = p0; posarr[e1] = p1; posarr[e2] = p2; posarr[e3] = p3;
        atomicAdd(&h[p0 >> BKT_SHIFT], 1);
        atomicAdd(&h[p1 >> BKT_SHIFT], 1);
        atomicAdd(&h[p2 >> BKT_SHIFT], 1);
        atomicAdd(&h[p3 >> BKT_SHIFT], 1);
    }
    for (; e < end; e += 256) {
        int d = dst[e];
        int c = e / chunk;
        int p = offsets[d] + (int)pre8[(size_t)c * N + d] + (int)rank8[e];
        posarr[e] = p;
        atomicAdd(&h[p >> BKT_SHIFT], 1);
    }
    __syncthreads();
    for (int b = threadIdx.x; b < nbuk; b += 256) cnt[(size_t)b * NBLK + blk] = h[b];
}

// ---------------- k_part2: dense-bucketed pair write ----------------
__global__ __launch_bounds__(256) void k_part2(const int* __restrict__ ei, int E, int epb, int nbuk,
                                               const int* __restrict__ cbase,
                                               const int* __restrict__ posarr,
                                               int2* __restrict__ pairs) {
    __shared__ int lb[512];
    int blk = blockIdx.x;
    for (int b = threadIdx.x; b < nbuk; b += 256) lb[b] = cbase[(size_t)b * NBLK + blk];
    __syncthreads();
    int beg = blk * epb;
    int end = min(E, beg + epb);
    for (int e = beg + threadIdx.x; e < end; e += 256) {
        int s = ei[e];
        int p = posarr[e];
        int slot = atomicAdd(&lb[p >> BKT_SHIFT], 1);
        pairs[slot] = make_int2(s, p);
    }
}

// ---------------- k_scat2: bucket-local dense final scatter ----------------
__global__ __launch_bounds__(256) void k_scat2(const int2* __restrict__ pairs, int E,
                                               int* __restrict__ csr_src) {
    int t = blockIdx.x * 256 + threadIdx.x;
    int e0 = t * 2;
    if (e0 + 1 < E) {
        int4 two = ((const int4*)pairs)[t];
        csr_src[two.y] = two.x;
        csr_src[two.w] = two.z;
    } else if (e0 < E) {
        int2 pr = pairs[e0];
        csr_src[pr.y] = pr.x;
    }
}

// ---------------- cast + pre-scale x: xh[i] = half(x[i] * dinv[node]) ----------------
__global__ __launch_bounds__(256) void k_cast32(const float* __restrict__ x, const float* __restrict__ dinv,
                                                __half* __restrict__ xh, int N) {
    int i = blockIdx.x * 256 + threadIdx.x;  // group of 4 elems
    if (i >= N * 8) return;
    int g = i >> 3;
    float di = dinv[g];
    float4 v = ((const float4*)x)[i];
    __half2 h0 = __floats2half2_rn(v.x * di, v.y * di);
    __half2 h1 = __floats2half2_rn(v.z * di, v.w * di);
    ((__half2*)xh)[2 * i] = h0;
    ((__half2*)xh)[2 * i + 1] = h1;
}

// ---------------- aggregation: 8 features per lane (16 B gathers) ----------------
template <int F>
__global__ __launch_bounds__(256) void k_agg(const __half* __restrict__ feat,
                                             const int* __restrict__ offsets,
                                             const int* __restrict__ csr_src,
                                             const float* __restrict__ dinv,
                                             float* __restrict__ out, int N) {
    constexpr int L = F / 8;  // lanes per node
    int t = blockIdx.x * 256 + threadIdx.x;
    int g = t / L;
    int q = t % L;            // feature octet index
    if (g >= N) return;
    const h2x4* f8 = (const h2x4*)feat;
    int beg = offsets[g];
    int end = offsets[g + 1];
    float di = dinv[g];
    float acc[8];
    {
        h2x4 w = f8[(size_t)g * L + q];
        float2 p0 = __half22float2(w.a), p1 = __half22float2(w.b);
        float2 p2 = __half22float2(w.c), p3 = __half22float2(w.d);
        acc[0] = p0.x; acc[1] = p0.y; acc[2] = p1.x; acc[3] = p1.y;
        acc[4] = p2.x; acc[5] = p2.y; acc[6] = p3.x; acc[7] = p3.y;
    }
    int e = beg;
    for (; e + 4 <= end; e += 4) {
        int s0 = csr_src[e + 0], s1 = csr_src[e + 1], s2 = csr_src[e + 2], s3 = csr_src[e + 3];
        h2x4 w0 = f8[(size_t)s0 * L + q];
        h2x4 w1 = f8[(size_t)s1 * L + q];
        h2x4 w2 = f8[(size_t)s2 * L + q];
        h2x4 w3 = f8[(size_t)s3 * L + q];
        float2 u;
        u = __half22float2(w0.a); acc[0] += u.x; acc[1] += u.y;
        u = __half22float2(w0.b); acc[2] += u.x; acc[3] += u.y;
        u = __half22float2(w0.c); acc[4] += u.x; acc[5] += u.y;
        u = __half22float2(w0.d); acc[6] += u.x; acc[7] += u.y;
        u = __half22float2(w1.a); acc[0] += u.x; acc[1] += u.y;
        u = __half22float2(w1.b); acc[2] += u.x; acc[3] += u.y;
        u = __half22float2(w1.c); acc[4] += u.x; acc[5] += u.y;
        u = __half22float2(w1.d); acc[6] += u.x; acc[7] += u.y;
        u = __half22float2(w2.a); acc[0] += u.x; acc[1] += u.y;
        u = __half22float2(w2.b); acc[2] += u.x; acc[3] += u.y;
        u = __half22float2(w2.c); acc[4] += u.x; acc[5] += u.y;
        u = __half22float2(w2.d); acc[6] += u.x; acc[7] += u.y;
        u = __half22float2(w3.a); acc[0] += u.x; acc[1] += u.y;
        u = __half22float2(w3.b); acc[2] += u.x; acc[3] += u.y;
        u = __half22float2(w3.c); acc[4] += u.x; acc[5] += u.y;
        u = __half22float2(w3.d); acc[6] += u.x; acc[7] += u.y;
    }
    for (; e < end; ++e) {
        h2x4 w = f8[(size_t)csr_src[e] * L + q];
        float2 u;
        u = __half22float2(w.a); acc[0] += u.x; acc[1] += u.y;
        u = __half22float2(w.b); acc[2] += u.x; acc[3] += u.y;
        u = __half22float2(w.c); acc[4] += u.x; acc[5] += u.y;
        u = __half22float2(w.d); acc[6] += u.x; acc[7] += u.y;
    }
    float4 o0 = make_float4(acc[0] * di, acc[1] * di, acc[2] * di, acc[3] * di);
    float4 o1 = make_float4(acc[4] * di, acc[5] * di, acc[6] * di, acc[7] * di);
    ((float4*)out)[(size_t)g * (F / 4) + q * 2] = o0;
    ((float4*)out)[(size_t)g * (F / 4) + q * 2 + 1] = o1;
}

// ---------------- GEMM1: h2h = half( relu(A[Nx32] @ W1 + b1) * dinv[row] ) ----------------
__global__ __launch_bounds__(256) void k_gemm1(const float* __restrict__ A, const float* __restrict__ W,
                                               const float* __restrict__ b, const float* __restrict__ dinv,
                                               __half* __restrict__ out, int N) {
    __shared__ float sA[32][68];
    __shared__ float sW[32][64];
    int tid = threadIdx.x;
    int row0 = blockIdx.x * 64;

    {
        const float4* Wv = (const float4*)W;
        float4* sWv = (float4*)&sW[0][0];
        sWv[tid] = Wv[tid];
        sWv[tid + 256] = Wv[tid + 256];
    }
    {
        int row = tid >> 2;
        int gr = row0 + row;
        int kq = (tid & 3) * 4;
#pragma unroll
        for (int i = 0; i < 2; ++i) {
            int k0 = kq + 16 * i;
            float4 v = (gr < N) ? *(const float4*)(A + (size_t)gr * 32 + k0)
                                : make_float4(0.f, 0.f, 0.f, 0.f);
            sA[k0 + 0][row] = v.x;
            sA[k0 + 1][row] = v.y;
            sA[k0 + 2][row] = v.z;
            sA[k0 + 3][row] = v.w;
        }
    }
    __syncthreads();

    int tm = tid & 15, tn = tid >> 4;
    float acc[4][4];
#pragma unroll
    for (int i = 0; i < 4; ++i) {
        float4 bb = *(const float4*)(b + tn * 4);
        acc[i][0] = bb.x; acc[i][1] = bb.y; acc[i][2] = bb.z; acc[i][3] = bb.w;
    }
#pragma unroll 4
    for (int k = 0; k < 32; ++k) {
        float4 a = *(const float4*)&sA[k][tm * 4];
        float4 w = *(const float4*)&sW[k][tn * 4];
        float av[4] = {a.x, a.y, a.z, a.w};
        float wv[4] = {w.x, w.y, w.z, w.w};
#pragma unroll
        for (int i = 0; i < 4; ++i)
#pragma unroll
            for (int j = 0; j < 4; ++j) acc[i][j] = fmaf(av[i], wv[j], acc[i][j]);
    }
#pragma unroll
    for (int i = 0; i < 4; ++i) {
        int row = row0 + tm * 4 + i;
        if (row < N) {
            float di = dinv[row];
            __half2 p0 = __floats2half2_rn(fmaxf(acc[i][0], 0.f) * di, fmaxf(acc[i][1], 0.f) * di);
            __half2 p1 = __floats2half2_rn(fmaxf(acc[i][2], 0.f) * di, fmaxf(acc[i][3], 0.f) * di);
            __half2* op = (__half2*)(out + (size_t)row * 64);
            op[tn * 2] = p0;
            op[tn * 2 + 1] = p1;
        }
    }
}

// ---------------- GEMM2: out = A[Nx64] @ W2[64x128] + b2 ----------------
__global__ __launch_bounds__(256) void k_gemm2(const float* __restrict__ A, const float* __restrict__ W,
                                               const float* __restrict__ b, float* __restrict__ out, int N) {
    __shared__ float sA[64][68];
    __shared__ float sW[64][128];
    int tid = threadIdx.x;
    int row0 = blockIdx.x * 64;

    {
        const float4* Wv = (const float4*)W;
        float4* sWv = (float4*)&sW[0][0];
#pragma unroll
        for (int i = 0; i < 8; ++i) sWv[tid + 256 * i] = Wv[tid + 256 * i];
    }
    {
        int row = tid >> 2;
        int gr = row0 + row;
        int kq = (tid & 3) * 4;
#pragma unroll
        for (int i = 0; i < 4; ++i) {
            int k0 = kq + 16 * i;
            float4 v = (gr < N) ? *(const float4*)(A + (size_t)gr * 64 + k0)
                                : make_float4(0.f, 0.f, 0.f, 0.f);
            sA[k0 + 0][row] = v.x;
            sA[k0 + 1][row] = v.y;
            sA[k0 + 2][row] = v.z;
            sA[k0 + 3][row] = v.w;
        }
    }
    __syncthreads();

    int tm = tid & 15, tn = tid >> 4;
    float acc[4][8];
    {
        float4 b0 = *(const float4*)(b + tn * 8);
        float4 b1 = *(const float4*)(b + tn * 8 + 4);
#pragma unroll
        for (int i = 0; i < 4; ++i) {
            acc[i][0] = b0.x; acc[i][1] = b0.y; acc[i][2] = b0.z; acc[i][3] = b0.w;
            acc[i][4] = b1.x; acc[i][5] = b1.y; acc[i][6] = b1.z; acc[i][7] = b1.w;
        }
    }
#pragma unroll 4
    for (int k = 0; k < 64; ++k) {
        float4 a = *(const float4*)&sA[k][tm * 4];
        float4 w0 = *(const float4*)&sW[k][tn * 8];
        float4 w1 = *(const float4*)&sW[k][tn * 8 + 4];
        float av[4] = {a.x, a.y, a.z, a.w};
        float wv[8] = {w0.x, w0.y, w0.z, w0.w, w1.x, w1.y, w1.z, w1.w};
#pragma unroll
        for (int i = 0; i < 4; ++i)
#pragma unroll
            for (int j = 0; j < 8; ++j) acc[i][j] = fmaf(av[i], wv[j], acc[i][j]);
    }
#pragma unroll
    for (int i = 0; i < 4; ++i) {
        int row = row0 + tm * 4 + i;
        if (row < N) {
            *(float4*)(out + (size_t)row * 128 + tn * 8) =
                make_float4(acc[i][0], acc[i][1], acc[i][2], acc[i][3]);
            *(float4*)(out + (size_t)row * 128 + tn * 8 + 4) =
                make_float4(acc[i][4], acc[i][5], acc[i][6], acc[i][7]);
        }
    }
}

extern "C" void kernel_launch(void* const* d_in, const int* in_sizes, int n_in,
                              void* d_out, int out_size, void* d_ws, size_t ws_size,
                              hipStream_t stream) {
    const float* x  = (const float*)d_in[0];
    const int*   ei = (const int*)d_in[1];
    const float* W1 = (const float*)d_in[2];
    const float* b1 = (const float*)d_in[3];
    const float* W2 = (const float*)d_in[4];
    const float* b2 = (const float*)d_in[5];
    float* out = (float*)d_out;

    const int N = in_sizes[0] / 32;
    const int E = in_sizes[1] / 2;
    const int chunk = cdiv(E, HC);
    const int epb = cdiv(E, NBLK);
    const int nbuk = cdiv(E, 1 << BKT_SHIFT);   // 391 for E=1.6M (<=512)
    const int clen = nbuk * NBLK;               // count-matrix length

    char* ws = (char*)d_ws;
    size_t off = 0;
    auto walloc = [&](size_t bytes) -> void* {
        void* p = ws + off;
        off = (off + bytes + 255) & ~(size_t)255;
        return p;
    };
    unsigned char* Mb      = (unsigned char*) walloc((size_t)HC * N);        // 6.4 MB
    unsigned char* pre8    = (unsigned char*) walloc((size_t)HC * N);        // 6.4 MB
    int*           deg     = (int*)           walloc((size_t)N * 4);
    float*         dinv    = (float*)         walloc((size_t)N * 4);
    int*           offsets = (int*)           walloc((size_t)(N + 4) * 4);
    int*           bsum    = (int*)           walloc(128 * 4);
    int*           boff    = (int*)           walloc(128 * 4);
    unsigned char* rank8   = (unsigned char*) walloc((size_t)E);             // 1.6 MB
    int*           posarr  = (int*)           walloc((size_t)E * 4);         // 6.4 MB
    int*           cnt     = (int*)           walloc((size_t)(clen + 4) * 4);
    int*           cbase   = (int*)           walloc((size_t)(clen + 4) * 4);
    int2*          pairs   = (int2*)          walloc((size_t)E * 8);         // 12.8 MB
    int*           csr_src = (int*)           walloc((size_t)E * 4);         // 6.4 MB
    __half*        xh      = (__half*)        walloc((size_t)N * 32 * 2);
    float*         a1      = (float*)         walloc((size_t)N * 32 * 4);
    __half*        h2h     = (__half*)        walloc((size_t)N * 64 * 2);
    float*         a2      = (float*)         walloc((size_t)N * 64 * 4);
    (void)ws_size; (void)n_in; (void)out_size;

    k_hist<<<HC, 1024, 0, stream>>>(ei + E, E, N, chunk, rank8, Mb);
    k_degpre<<<cdiv(N / 4, 256), 256, 0, stream>>>(Mb, N, pre8, deg, dinv);

    const int NB = cdiv(N, SCAN_BS);
    k_blocksum<<<NB, SCAN_BS, 0, stream>>>(deg, N, bsum);
    k_scan_bsums<<<1, 128, 0, stream>>>(bsum, NB, boff);
    k_scan_final<<<NB, SCAN_BS, 0, stream>>>(deg, N, boff, offsets, E);

    k_cast32<<<cdiv(N * 8, 256), 256, 0, stream>>>(x, dinv, xh, N);

    // bucketed permutation: pos -> (dense pairs) -> csr
    k_pos<<<NBLK, 256, 0, stream>>>(ei, E, N, chunk, epb, nbuk, offsets, pre8, rank8, posarr, cnt);
    const int NB2 = cdiv(clen, SCAN_BS);
    k_blocksum<<<NB2, SCAN_BS, 0, stream>>>(cnt, clen, bsum);
    k_scan_bsums<<<1, 128, 0, stream>>>(bsum, NB2, boff);
    k_scan_final<<<NB2, SCAN_BS, 0, stream>>>(cnt, clen, boff, cbase, E);
    k_part2<<<NBLK, 256, 0, stream>>>(ei, E, epb, nbuk, cbase, posarr, pairs);
    k_scat2<<<cdiv(E, 512), 256, 0, stream>>>(pairs, E, csr_src);

    k_agg<32><<<cdiv(N * 4, 256), 256, 0, stream>>>(xh, offsets, csr_src, dinv, a1, N);
    k_gemm1<<<cdiv(N, 64), 256, 0, stream>>>(a1, W1, b1, dinv, h2h, N);

    k_agg<64><<<cdiv(N * 8, 256), 256, 0, stream>>>(h2h, offsets, csr_src, dinv, a2, N);
    k_gemm2<<<cdiv(N, 64), 256, 0, stream>>>(a2, W2, b2, out, N);
}

// Round 13
// 167.289 us; speedup vs baseline: 1.1186x; 1.1186x over previous
//
#include <hip/hip_runtime.h>
#include <hip/hip_fp16.h>

static inline int cdiv(int a, int b) { return (a + b - 1) / b; }

#define NWORD 25600   // 102400 B LDS = byte counters for N <= 102400
#define HC    64      // edge chunks (= hist blocks)
#define NPART 8       // XCD partitions
#define SUB   256     // edge sub-ranges for partitioned scatter

struct h2x4 { __half2 a, b, c, d; };  // 16 B = 8 halves

// ---------------- phase A: single-pass full-range LDS histogram + rank ----------------
__global__ __launch_bounds__(1024) void k_hist(const int* __restrict__ dst, int E, int N, int chunk,
                                               unsigned char* __restrict__ rank8,
                                               unsigned char* __restrict__ Mb) {
    __shared__ unsigned int cnt[NWORD];
    int c = blockIdx.x;
    for (int i = threadIdx.x; i < NWORD; i += 1024) cnt[i] = 0;
    __syncthreads();
    int ebeg = c * chunk;
    int eend = min(E, ebeg + chunk);
    for (int e = ebeg + threadIdx.x; e < eend; e += 1024) {
        int d = dst[e];
        int sh = (d & 3) * 8;
        unsigned int old = atomicAdd(&cnt[d >> 2], 1u << sh);  // LDS atomic
        rank8[e] = (unsigned char)((old >> sh) & 0xFF);
    }
    __syncthreads();
    unsigned int* Mrow = (unsigned int*)(Mb + (size_t)c * N);
    int nw = N >> 2;
    for (int i = threadIdx.x; i < nw; i += 1024) Mrow[i] = cnt[i];
}

// ---------------- deg + dinv + per-(chunk,node) byte prefix (fused) ----------------
__global__ __launch_bounds__(256) void k_degpre(const unsigned char* __restrict__ Mb, int N,
                                                unsigned char* __restrict__ pre8,
                                                int* __restrict__ deg, float* __restrict__ dinv) {
    int i = blockIdx.x * 256 + threadIdx.x;  // group of 4 nodes
    if (i >= (N >> 2)) return;
    unsigned int s0 = 0, s1 = 0, s2 = 0, s3 = 0;
#pragma unroll
    for (int c = 0; c < HC; ++c) {
        unsigned int w = *(const unsigned int*)(Mb + (size_t)c * N + 4 * i);
        *(unsigned int*)(pre8 + (size_t)c * N + 4 * i) = s0 | (s1 << 8) | (s2 << 16) | (s3 << 24);
        s0 += w & 0xFF; s1 += (w >> 8) & 0xFF; s2 += (w >> 16) & 0xFF; s3 += (w >> 24) & 0xFF;
    }
    ((int4*)deg)[i] = make_int4((int)s0, (int)s1, (int)s2, (int)s3);
    ((float4*)dinv)[i] = make_float4(rsqrtf((float)(s0 + 1)), rsqrtf((float)(s1 + 1)),
                                     rsqrtf((float)(s2 + 1)), rsqrtf((float)(s3 + 1)));
}

// ---------------- exclusive scan (hierarchical) ----------------
#define SCAN_BS 1024

__global__ __launch_bounds__(SCAN_BS) void k_blocksum(const int* __restrict__ deg, int N, int* __restrict__ bsum) {
    __shared__ int s[SCAN_BS];
    int t = threadIdx.x;
    int i = blockIdx.x * SCAN_BS + t;
    s[t] = (i < N) ? deg[i] : 0;
    __syncthreads();
    for (int off = SCAN_BS / 2; off > 0; off >>= 1) {
        if (t < off) s[t] += s[t + off];
        __syncthreads();
    }
    if (t == 0) bsum[blockIdx.x] = s[0];
}

__global__ __launch_bounds__(128) void k_scan_bsums(const int* __restrict__ bsum, int NB, int* __restrict__ boff) {
    __shared__ int s[128];
    int t = threadIdx.x;
    int v = (t < NB) ? bsum[t] : 0;
    s[t] = v;
    __syncthreads();
    for (int off = 1; off < 128; off <<= 1) {
        int u = (t >= off) ? s[t - off] : 0;
        __syncthreads();
        s[t] += u;
        __syncthreads();
    }
    if (t < NB) boff[t] = s[t] - v;  // exclusive
}

__global__ __launch_bounds__(SCAN_BS) void k_scan_final(const int* __restrict__ deg, int N,
                                                        const int* __restrict__ boff,
                                                        int* __restrict__ offsets, int E) {
    __shared__ int s[SCAN_BS];
    int t = threadIdx.x;
    int i = blockIdx.x * SCAN_BS + t;
    int v = (i < N) ? deg[i] : 0;
    s[t] = v;
    __syncthreads();
    for (int off = 1; off < SCAN_BS; off <<= 1) {
        int u = (t >= off) ? s[t - off] : 0;
        __syncthreads();
        s[t] += u;
        __syncthreads();
    }
    if (i < N) offsets[i] = boff[blockIdx.x] + s[t] - v;
    if (blockIdx.x == 0 && t == 0) offsets[N] = E;
}

// ---------------- XCD-partitioned scatter: zero atomics, XCD-local writes ----------------
// Block p=blockIdx&7 handles dst partition p; each edge written exactly once.
__global__ __launch_bounds__(256) void k_scatter_part(const int* __restrict__ ei, int E, int N, int chunk,
                                                      int espb, int part,
                                                      const int* __restrict__ offsets,
                                                      const unsigned char* __restrict__ pre8,
                                                      const unsigned char* __restrict__ rank8,
                                                      int* __restrict__ csr_src) {
    int p = blockIdx.x & (NPART - 1);
    int sub = blockIdx.x >> 3;
    int lo = p * part;
    int hi = min(N, lo + part);
    int beg = sub * espb;
    int end = min(E, beg + espb);
    const int* dst = ei + E;
    for (int e = beg + threadIdx.x; e < end; e += 256) {
        int d = dst[e];
        if (d >= lo && d < hi) {
            int c = e / chunk;
            int pos = offsets[d] + (int)pre8[(size_t)c * N + d] + (int)rank8[e];
            csr_src[pos] = ei[e];
        }
    }
}

// ---------------- cast + pre-scale x: xh[i] = half(x[i] * dinv[node]) ----------------
__global__ __launch_bounds__(256) void k_cast32(const float* __restrict__ x, const float* __restrict__ dinv,
                                                __half* __restrict__ xh, int N) {
    int i = blockIdx.x * 256 + threadIdx.x;  // group of 4 elems
    if (i >= N * 8) return;
    int g = i >> 3;
    float di = dinv[g];
    float4 v = ((const float4*)x)[i];
    __half2 h0 = __floats2half2_rn(v.x * di, v.y * di);
    __half2 h1 = __floats2half2_rn(v.z * di, v.w * di);
    ((__half2*)xh)[2 * i] = h0;
    ((__half2*)xh)[2 * i + 1] = h1;
}

// ---------------- aggregation: 8 features per lane (16 B gathers) ----------------
template <int F>
__global__ __launch_bounds__(256) void k_agg(const __half* __restrict__ feat,
                                             const int* __restrict__ offsets,
                                             const int* __restrict__ csr_src,
                                             const float* __restrict__ dinv,
                                             float* __restrict__ out, int N) {
    constexpr int L = F / 8;  // lanes per node
    int t = blockIdx.x * 256 + threadIdx.x;
    int g = t / L;
    int q = t % L;            // feature octet index
    if (g >= N) return;
    const h2x4* f8 = (const h2x4*)feat;
    int beg = offsets[g];
    int end = offsets[g + 1];
    float di = dinv[g];
    float acc[8];
    {
        h2x4 w = f8[(size_t)g * L + q];
        float2 p0 = __half22float2(w.a), p1 = __half22float2(w.b);
        float2 p2 = __half22float2(w.c), p3 = __half22float2(w.d);
        acc[0] = p0.x; acc[1] = p0.y; acc[2] = p1.x; acc[3] = p1.y;
        acc[4] = p2.x; acc[5] = p2.y; acc[6] = p3.x; acc[7] = p3.y;
    }
    int e = beg;
    for (; e + 4 <= end; e += 4) {
        int s0 = csr_src[e + 0], s1 = csr_src[e + 1], s2 = csr_src[e + 2], s3 = csr_src[e + 3];
        h2x4 w0 = f8[(size_t)s0 * L + q];
        h2x4 w1 = f8[(size_t)s1 * L + q];
        h2x4 w2 = f8[(size_t)s2 * L + q];
        h2x4 w3 = f8[(size_t)s3 * L + q];
        float2 u;
        u = __half22float2(w0.a); acc[0] += u.x; acc[1] += u.y;
        u = __half22float2(w0.b); acc[2] += u.x; acc[3] += u.y;
        u = __half22float2(w0.c); acc[4] += u.x; acc[5] += u.y;
        u = __half22float2(w0.d); acc[6] += u.x; acc[7] += u.y;
        u = __half22float2(w1.a); acc[0] += u.x; acc[1] += u.y;
        u = __half22float2(w1.b); acc[2] += u.x; acc[3] += u.y;
        u = __half22float2(w1.c); acc[4] += u.x; acc[5] += u.y;
        u = __half22float2(w1.d); acc[6] += u.x; acc[7] += u.y;
        u = __half22float2(w2.a); acc[0] += u.x; acc[1] += u.y;
        u = __half22float2(w2.b); acc[2] += u.x; acc[3] += u.y;
        u = __half22float2(w2.c); acc[4] += u.x; acc[5] += u.y;
        u = __half22float2(w2.d); acc[6] += u.x; acc[7] += u.y;
        u = __half22float2(w3.a); acc[0] += u.x; acc[1] += u.y;
        u = __half22float2(w3.b); acc[2] += u.x; acc[3] += u.y;
        u = __half22float2(w3.c); acc[4] += u.x; acc[5] += u.y;
        u = __half22float2(w3.d); acc[6] += u.x; acc[7] += u.y;
    }
    for (; e < end; ++e) {
        h2x4 w = f8[(size_t)csr_src[e] * L + q];
        float2 u;
        u = __half22float2(w.a); acc[0] += u.x; acc[1] += u.y;
        u = __half22float2(w.b); acc[2] += u.x; acc[3] += u.y;
        u = __half22float2(w.c); acc[4] += u.x; acc[5] += u.y;
        u = __half22float2(w.d); acc[6] += u.x; acc[7] += u.y;
    }
    float4 o0 = make_float4(acc[0] * di, acc[1] * di, acc[2] * di, acc[3] * di);
    float4 o1 = make_float4(acc[4] * di, acc[5] * di, acc[6] * di, acc[7] * di);
    ((float4*)out)[(size_t)g * (F / 4) + q * 2] = o0;
    ((float4*)out)[(size_t)g * (F / 4) + q * 2 + 1] = o1;
}

// ---------------- GEMM1: h2h = half( relu(A[Nx32] @ W1 + b1) * dinv[row] ) ----------------
__global__ __launch_bounds__(256) void k_gemm1(const float* __restrict__ A, const float* __restrict__ W,
                                               const float* __restrict__ b, const float* __restrict__ dinv,
                                               __half* __restrict__ out, int N) {
    __shared__ float sA[32][68];
    __shared__ float sW[32][64];
    int tid = threadIdx.x;
    int row0 = blockIdx.x * 64;

    {
        const float4* Wv = (const float4*)W;
        float4* sWv = (float4*)&sW[0][0];
        sWv[tid] = Wv[tid];
        sWv[tid + 256] = Wv[tid + 256];
    }
    {
        int row = tid >> 2;
        int gr = row0 + row;
        int kq = (tid & 3) * 4;
#pragma unroll
        for (int i = 0; i < 2; ++i) {
            int k0 = kq + 16 * i;
            float4 v = (gr < N) ? *(const float4*)(A + (size_t)gr * 32 + k0)
                                : make_float4(0.f, 0.f, 0.f, 0.f);
            sA[k0 + 0][row] = v.x;
            sA[k0 + 1][row] = v.y;
            sA[k0 + 2][row] = v.z;
            sA[k0 + 3][row] = v.w;
        }
    }
    __syncthreads();

    int tm = tid & 15, tn = tid >> 4;
    float acc[4][4];
#pragma unroll
    for (int i = 0; i < 4; ++i) {
        float4 bb = *(const float4*)(b + tn * 4);
        acc[i][0] = bb.x; acc[i][1] = bb.y; acc[i][2] = bb.z; acc[i][3] = bb.w;
    }
#pragma unroll 4
    for (int k = 0; k < 32; ++k) {
        float4 a = *(const float4*)&sA[k][tm * 4];
        float4 w = *(const float4*)&sW[k][tn * 4];
        float av[4] = {a.x, a.y, a.z, a.w};
        float wv[4] = {w.x, w.y, w.z, w.w};
#pragma unroll
        for (int i = 0; i < 4; ++i)
#pragma unroll
            for (int j = 0; j < 4; ++j) acc[i][j] = fmaf(av[i], wv[j], acc[i][j]);
    }
#pragma unroll
    for (int i = 0; i < 4; ++i) {
        int row = row0 + tm * 4 + i;
        if (row < N) {
            float di = dinv[row];
            __half2 p0 = __floats2half2_rn(fmaxf(acc[i][0], 0.f) * di, fmaxf(acc[i][1], 0.f) * di);
            __half2 p1 = __floats2half2_rn(fmaxf(acc[i][2], 0.f) * di, fmaxf(acc[i][3], 0.f) * di);
            __half2* op = (__half2*)(out + (size_t)row * 64);
            op[tn * 2] = p0;
            op[tn * 2 + 1] = p1;
        }
    }
}

// ---------------- GEMM2: out = A[Nx64] @ W2[64x128] + b2 ----------------
__global__ __launch_bounds__(256) void k_gemm2(const float* __restrict__ A, const float* __restrict__ W,
                                               const float* __restrict__ b, float* __restrict__ out, int N) {
    __shared__ float sA[64][68];
    __shared__ float sW[64][128];
    int tid = threadIdx.x;
    int row0 = blockIdx.x * 64;

    {
        const float4* Wv = (const float4*)W;
        float4* sWv = (float4*)&sW[0][0];
#pragma unroll
        for (int i = 0; i < 8; ++i) sWv[tid + 256 * i] = Wv[tid + 256 * i];
    }
    {
        int row = tid >> 2;
        int gr = row0 + row;
        int kq = (tid & 3) * 4;
#pragma unroll
        for (int i = 0; i < 4; ++i) {
            int k0 = kq + 16 * i;
            float4 v = (gr < N) ? *(const float4*)(A + (size_t)gr * 64 + k0)
                                : make_float4(0.f, 0.f, 0.f, 0.f);
            sA[k0 + 0][row] = v.x;
            sA[k0 + 1][row] = v.y;
            sA[k0 + 2][row] = v.z;
            sA[k0 + 3][row] = v.w;
        }
    }
    __syncthreads();

    int tm = tid & 15, tn = tid >> 4;
    float acc[4][8];
    {
        float4 b0 = *(const float4*)(b + tn * 8);
        float4 b1 = *(const float4*)(b + tn * 8 + 4);
#pragma unroll
        for (int i = 0; i < 4; ++i) {
            acc[i][0] = b0.x; acc[i][1] = b0.y; acc[i][2] = b0.z; acc[i][3] = b0.w;
            acc[i][4] = b1.x; acc[i][5] = b1.y; acc[i][6] = b1.z; acc[i][7] = b1.w;
        }
    }
#pragma unroll 4
    for (int k = 0; k < 64; ++k) {
        float4 a = *(const float4*)&sA[k][tm * 4];
        float4 w0 = *(const float4*)&sW[k][tn * 8];
        float4 w1 = *(const float4*)&sW[k][tn * 8 + 4];
        float av[4] = {a.x, a.y, a.z, a.w};
        float wv[8] = {w0.x, w0.y, w0.z, w0.w, w1.x, w1.y, w1.z, w1.w};
#pragma unroll
        for (int i = 0; i < 4; ++i)
#pragma unroll
            for (int j = 0; j < 8; ++j) acc[i][j] = fmaf(av[i], wv[j], acc[i][j]);
    }
#pragma unroll
    for (int i = 0; i < 4; ++i) {
        int row = row0 + tm * 4 + i;
        if (row < N) {
            *(float4*)(out + (size_t)row * 128 + tn * 8) =
                make_float4(acc[i][0], acc[i][1], acc[i][2], acc[i][3]);
            *(float4*)(out + (size_t)row * 128 + tn * 8 + 4) =
                make_float4(acc[i][4], acc[i][5], acc[i][6], acc[i][7]);
        }
    }
}

extern "C" void kernel_launch(void* const* d_in, const int* in_sizes, int n_in,
                              void* d_out, int out_size, void* d_ws, size_t ws_size,
                              hipStream_t stream) {
    const float* x  = (const float*)d_in[0];
    const int*   ei = (const int*)d_in[1];
    const float* W1 = (const float*)d_in[2];
    const float* b1 = (const float*)d_in[3];
    const float* W2 = (const float*)d_in[4];
    const float* b2 = (const float*)d_in[5];
    float* out = (float*)d_out;

    const int N = in_sizes[0] / 32;
    const int E = in_sizes[1] / 2;
    const int chunk = cdiv(E, HC);
    const int espb = cdiv(E, SUB);
    const int part = cdiv(N, NPART);

    char* ws = (char*)d_ws;
    size_t off = 0;
    auto walloc = [&](size_t bytes) -> void* {
        void* p = ws + off;
        off = (off + bytes + 255) & ~(size_t)255;
        return p;
    };
    unsigned char* Mb      = (unsigned char*) walloc((size_t)HC * N);        // 6.4 MB
    unsigned char* pre8    = (unsigned char*) walloc((size_t)HC * N);        // 6.4 MB
    int*           deg     = (int*)           walloc((size_t)N * 4);
    float*         dinv    = (float*)         walloc((size_t)N * 4);
    int*           offsets = (int*)           walloc((size_t)(N + 4) * 4);
    int*           bsum    = (int*)           walloc(128 * 4);
    int*           boff    = (int*)           walloc(128 * 4);
    unsigned char* rank8   = (unsigned char*) walloc((size_t)E);             // 1.6 MB
    int*           csr_src = (int*)           walloc((size_t)E * 4);         // 6.4 MB
    __half*        xh      = (__half*)        walloc((size_t)N * 32 * 2);    // 6.4 MB
    float*         a1      = (float*)         walloc((size_t)N * 32 * 4);    // 12.8 MB
    __half*        h2h     = (__half*)        walloc((size_t)N * 64 * 2);    // 12.8 MB
    float*         a2      = (float*)         walloc((size_t)N * 64 * 4);    // 25.6 MB
    (void)ws_size; (void)n_in; (void)out_size;

    k_hist<<<HC, 1024, 0, stream>>>(ei + E, E, N, chunk, rank8, Mb);
    k_degpre<<<cdiv(N / 4, 256), 256, 0, stream>>>(Mb, N, pre8, deg, dinv);

    const int NB = cdiv(N, SCAN_BS);
    k_blocksum<<<NB, SCAN_BS, 0, stream>>>(deg, N, bsum);
    k_scan_bsums<<<1, 128, 0, stream>>>(bsum, NB, boff);
    k_scan_final<<<NB, SCAN_BS, 0, stream>>>(deg, N, boff, offsets, E);

    k_cast32<<<cdiv(N * 8, 256), 256, 0, stream>>>(x, dinv, xh, N);
    k_scatter_part<<<NPART * SUB, 256, 0, stream>>>(ei, E, N, chunk, espb, part,
                                                    offsets, pre8, rank8, csr_src);

    k_agg<32><<<cdiv(N * 4, 256), 256, 0, stream>>>(xh, offsets, csr_src, dinv, a1, N);
    k_gemm1<<<cdiv(N, 64), 256, 0, stream>>>(a1, W1, b1, dinv, h2h, N);

    k_agg<64><<<cdiv(N * 8, 256), 256, 0, stream>>>(h2h, offsets, csr_src, dinv, a2, N);
    k_gemm2<<<cdiv(N, 64), 256, 0, stream>>>(a2, W2, b2, out, N);
}